// Round 10
// baseline (684.951 us; speedup 1.0000x reference)
//
#include <hip/hip_runtime.h>
#include <hip/hip_bf16.h>

// Problem constants
#define NS 2560      // B*N sentences
#define NT 70        // tokens per sentence
#define NH 200       // hidden
#define NHP 208      // padded h row stride (16B-aligned rows for f16 stores)
#define NI 60        // input dim (50 + 5 + 5)
#define XSTR 64      // padded x row stride (zeros in [60,64))
#define NREL 100
#define NBAG 128
#define NPB 20       // sentences per bag

#define NTRI 13      // gate triples of 16 (13*16 = 208 >= 200)
#define FR128 2048   // bytes per K=128 fragment (64 lanes x 32)

// h history layout: [s][t][NHP] f16 (R9; net-zero vs [t][s], kept)
#define HROW ((long)NT * NHP)

// Packed weight layout per dir (K=128 MX fragments, fp8 e4m3, scale=1.0):
//   h-part: [tri 13][kinst 2][seg 3][2048] = 159,744 B  (K=256 padded, k>=200 zero)
//   x-part: [tri 13][seg 3][2048]          =  79,872 B  (K=128 padded, k>=60 zero)
#define WPK_H_BYTES (NTRI * 2 * 3 * FR128)   // 159,744
#define WPK_X_BYTES (NTRI * 3 * FR128)       //  79,872
#define WPK_DIR_BYTES (WPK_H_BYTES + WPK_X_BYTES)

// Ah LDS: [2 buf][8 kgrp][32 row][48]  (row stride 48 = 16B-aligned for b128)
#define AH_STRIDE 48
#define AH_KGRP (32 * AH_STRIDE)     // 1536
#define AH_BUF (8 * AH_KGRP)         // 12288
#define AH_BYTES (2 * AH_BUF)        // 24576

typedef unsigned short ushort_t;
typedef unsigned char uchar_t;
typedef _Float16 h16;
typedef __attribute__((ext_vector_type(4))) float f32x4;
typedef int v2i __attribute__((ext_vector_type(2), aligned(4)));
typedef unsigned int v4u __attribute__((ext_vector_type(4), aligned(16)));
typedef int v8i __attribute__((ext_vector_type(8), aligned(16)));
typedef __attribute__((ext_vector_type(8))) _Float16 h16x8;

// fp8 MX MFMA with unit scales (E8M0 127 = 2^0): plain fp8 GEMM at 2.27x rate
#define MFMA128(A, B, C) \
    __builtin_amdgcn_mfma_scale_f32_16x16x128_f8f6f4((A), (B), (C), 0, 0, 0, 0x7F7F7F7F, 0, 0x7F7F7F7F)

// Fast activations: v_rcp_f32 (1 inst) instead of IEEE division chains
// (R8 mechanism: -130 us). Error invisible under fp8 quantization.
__device__ __forceinline__ float rcpf(float x) { return __builtin_amdgcn_rcpf(x); }
__device__ __forceinline__ float sigf(float x) { return rcpf(1.0f + __expf(-x)); }
__device__ __forceinline__ float tanh_fast(float x) {
    float e = __expf(2.0f * x);
    return 1.0f - 2.0f * rcpf(e + 1.0f);
}

// fp8 e4m3 (OCP on gfx950) encode, RTNE
__device__ __forceinline__ uchar_t f2fp8(float f) {
#if __has_builtin(__builtin_amdgcn_cvt_pk_fp8_f32)
    int p = __builtin_amdgcn_cvt_pk_fp8_f32(f, f, 0, false);
    return (uchar_t)(p & 0xff);
#else
    unsigned u = __float_as_uint(f);
    unsigned s = (u >> 24) & 0x80u;
    float a = fabsf(f);
    if (a >= 448.0f) return (uchar_t)(s | 0x7E);
    if (a < 0.015625f) {
        int q = (int)rintf(a * 512.0f);
        return (uchar_t)(s | (unsigned)q);
    }
    unsigned au = __float_as_uint(a);
    int e = (int)(au >> 23) - 127;
    unsigned m = au & 0x7fffffu;
    unsigned keep = m >> 20;
    unsigned rnd = (m >> 19) & 1u;
    unsigned sticky = (m & 0x7ffffu) ? 1u : 0u;
    keep += (rnd & (sticky | (keep & 1u)));
    int ee = e + 7;
    if (keep == 8u) { keep = 0u; ee += 1; }
    if (ee >= 16) return (uchar_t)(s | 0x7E);
    return (uchar_t)(s | ((unsigned)ee << 3) | keep);
#endif
}

// ---------------------------------------------------------------------------
// Pack weights into K=128 MFMA B-fragment order, fp8 e4m3, zero-padded.
// B-frag for 16x16x128 f8f6f4: lane ln holds col n=(ln&15), k=(ln>>4)*32+j,
// j=0..31 (one contiguous 32-k MX block per lane). n -> gate g = seg*200+16*tri+n.
// ---------------------------------------------------------------------------
__global__ void prep_wpk_kernel(const float* __restrict__ WihF, const float* __restrict__ WhhF,
                                const float* __restrict__ WihB, const float* __restrict__ WhhB,
                                uchar_t* __restrict__ Wpk) {
    int idx = blockIdx.x * 256 + threadIdx.x;
    const int total = 2 * WPK_DIR_BYTES;
    if (idx >= total) return;
    int d = idx / WPK_DIR_BYTES;
    int r = idx - d * WPK_DIR_BYTES;
    int tri, kinst, seg, e;
    bool isX;
    if (r < WPK_H_BYTES) {
        tri = r / 12288;
        int r2 = r % 12288;
        kinst = r2 / 6144;
        int r3 = r2 % 6144;
        seg = r3 / 2048;
        e = r3 % 2048;
        isX = false;
    } else {
        int r2 = r - WPK_H_BYTES;
        tri = r2 / 6144;
        int r3 = r2 % 6144;
        seg = r3 / 2048;
        e = r3 % 2048;
        kinst = 0;
        isX = true;
    }
    int ln = e >> 5;
    int j = e & 31;
    const float* Wih = d ? WihB : WihF;
    const float* Whh = d ? WhhB : WhhF;
    int gl = 16 * tri + (ln & 15);
    int k = kinst * 128 + ((ln >> 4) << 5) + j;
    float v = 0.0f;
    if (gl < NH) {
        int g = seg * NH + gl;
        if (isX) { if (k < NI) v = Wih[g * NI + k]; }
        else     { if (k < NH) v = Whh[g * NH + k]; }
    }
    Wpk[idx] = f2fp8(v);
}

// ---------------------------------------------------------------------------
// Gather x[t][s][d] = concat(word_emb, pos1_emb, pos2_emb), fp8,
// [70][2560][XSTR=64] with zeros in d in [60,64).
// ---------------------------------------------------------------------------
__global__ void gather_kernel(const int* __restrict__ tok, const int* __restrict__ p1,
                              const int* __restrict__ p2, const float* __restrict__ emb,
                              const float* __restrict__ pemb, uchar_t* __restrict__ x) {
    int idx = blockIdx.x * 256 + threadIdx.x;
    if (idx >= NT * NS * 16) return;
    int chunk = idx & 15;
    int st = idx >> 4;
    int s = st % NS;
    int t = st / NS;
    int o = s * NT + t;
    int d4 = chunk * 4;
    unsigned out = 0;
    #pragma unroll
    for (int e = 0; e < 4; e++) {
        int d = d4 + e;
        float v = 0.0f;
        if (d < 50)      v = emb[(long)tok[o] * 50 + d];
        else if (d < 55) v = pemb[p1[o] * 5 + (d - 50)];
        else if (d < 60) v = pemb[p2[o] * 5 + (d - 55)];
        out |= ((unsigned)f2fp8(v)) << (8 * e);
    }
    *(unsigned*)(x + ((long)t * NS + s) * XSTR + d4) = out;
}

// ---------------------------------------------------------------------------
// MX-MFMA GRU. 256 blocks (128 groups x 2 dirs) = 1 block/CU, 832 thr = 13
// waves. Wave w owns gate-triple w (gates [16w,16w+16) of r,z,n).
// R10 deltas vs R9 (one theme: shorten the post-barrier serial chain):
//  - x A-fragments prefetched ONE STEP AHEAD into registers, issued
//    post-barrier BEFORE the global h-stores (in-order vmcnt: their wait
//    never drains the store queue).
//  - MFMA order: ax-chain FIRST (zero-wait register operands), then a0/a1
//    (the exposed ds_read lgkm latency hides under the ax MFMAs).
//  - Biases in the MFMA C-operand (added once by HW; deletes 32 VALU adds
//    per thread-step from the epilogue). Isolated retest of R5's piece.
// B-fragments asm-pinned in registers; fast-rcp activations (R8).
// ---------------------------------------------------------------------------
__global__ __launch_bounds__(832, 4)
void gru_kernel(const uchar_t* __restrict__ x, const uchar_t* __restrict__ Wpk,
                const float* __restrict__ bihF, const float* __restrict__ bhhF,
                const float* __restrict__ bihB, const float* __restrict__ bhhB,
                h16* __restrict__ hfo, h16* __restrict__ hbo) {
    __shared__ __align__(16) uchar_t Ah[AH_BYTES];   // [2][8][32][48] fp8 A(h) dbuf

    const int dir = blockIdx.x >> 7;
    const int s0 = (blockIdx.x & 127) * NPB;
    const int tid = threadIdx.x;
    const int wv = tid >> 6, ln = tid & 63;
    const int c = ln & 15, quad = ln >> 4;
    const int jl = 16 * wv + c;
    const bool jv = jl < NH;

    const float* bih = dir ? bihB : bihF;
    const float* bhh = dir ? bhhB : bhhF;
    const uchar_t* wdir = Wpk + (long)dir * WPK_DIR_BYTES;
    h16* hd = dir ? hbo : hfo;

    const float br  = jv ? bih[jl] + bhh[jl] : 0.0f;
    const float bz  = jv ? bih[NH + jl] + bhh[NH + jl] : 0.0f;
    const float bnx = jv ? bih[2 * NH + jl] : 0.0f;
    const float bnh = jv ? bhh[2 * NH + jl] : 0.0f;

    // B fragments: loop-invariant -> registers, PINNED (asm-opaque so the
    // allocator cannot rematerialize them as per-step loads).
    v8i Bhh[6];
    v8i Bx[3];
    {
        const uchar_t* wh = wdir + wv * (6 * FR128) + ln * 32;
        #pragma unroll
        for (int i = 0; i < 6; i++) Bhh[i] = *(const v8i*)(wh + i * FR128);
        const uchar_t* wx = wdir + WPK_H_BYTES + wv * (3 * FR128) + ln * 32;
        #pragma unroll
        for (int i = 0; i < 3; i++) Bx[i] = *(const v8i*)(wx + i * FR128);
        #pragma unroll
        for (int i = 0; i < 6; i++) {
            #pragma unroll
            for (int j = 0; j < 8; j++) {
                int tmp = Bhh[i][j];
                asm volatile("" : "+v"(tmp));
                Bhh[i][j] = tmp;
            }
        }
        #pragma unroll
        for (int i = 0; i < 3; i++) {
            #pragma unroll
            for (int j = 0; j < 8; j++) {
                int tmp = Bx[i][j];
                asm volatile("" : "+v"(tmp));
                Bx[i][j] = tmp;
            }
        }
    }

    // zero Ah (h0 = 0; pad rows 20..31, cols 200..207, k 208..255 stay zero)
    for (int i = tid; i < AH_BYTES / 4; i += 832) ((unsigned*)Ah)[i] = 0u;
    __syncthreads();

    float hold[2][4] = {};   // [mt][reg], f32 carry (full precision recurrence)

    const long xstep = dir ? -(long)NS * XSTR : (long)NS * XSTR;
    const long hstep = dir ? -(long)NHP : (long)NHP;   // per-t step in [s][t] layout
    const uchar_t* xp = x + ((long)(dir ? NT - 1 : 0) * NS + s0) * XSTR;
    h16* hdt = hd + (long)s0 * HROW + (long)(dir ? NT - 1 : 0) * NHP;
    const long xoffA = (long)c * XSTR + quad * 32;
    const long xoffB = (long)(16 + c) * XSTR + quad * 32;

    // prologue: prefetch x A-fragments for t=0
    v8i axA = *(const v8i*)(xp + xoffA);
    v8i axB = *(const v8i*)(xp + xoffB);

    for (int t = 0; t < NT; t++) {
        const int cur = t & 1, nxt = cur ^ 1;
        const uchar_t* ac = Ah + cur * AH_BUF;
        uchar_t* an = Ah + nxt * AH_BUF;

        #pragma unroll
        for (int mt = 0; mt < 2; mt++) {
            const int row = mt * 16 + c;
            v8i ax = mt ? axB : axA;
            // h A-fragments from LDS: kinst0 -> kgrp quad, kinst1 -> kgrp 4+quad
            v8i a0 = *(const v8i*)(ac + quad * AH_KGRP + row * AH_STRIDE);
            v8i a1 = *(const v8i*)(ac + (4 + quad) * AH_KGRP + row * AH_STRIDE);

            // bias pre-loaded into the C-operand (HW adds it exactly once)
            f32x4 aR  = {br,  br,  br,  br};
            f32x4 aZ  = {bz,  bz,  bz,  bz};
            f32x4 aNH = {bnh, bnh, bnh, bnh};
            f32x4 aNX = {bnx, bnx, bnx, bnx};

            // x-chain first: register operands, starts with ZERO wait;
            // the ds_read lgkm latency for a0/a1 hides underneath.
            aR  = MFMA128(ax, Bx[0], aR);
            aZ  = MFMA128(ax, Bx[1], aZ);
            aNX = MFMA128(ax, Bx[2], aNX);
            aR  = MFMA128(a0, Bhh[0], aR);
            aZ  = MFMA128(a0, Bhh[1], aZ);
            aNH = MFMA128(a0, Bhh[2], aNH);
            aR  = MFMA128(a1, Bhh[3], aR);
            aZ  = MFMA128(a1, Bhh[4], aZ);
            aNH = MFMA128(a1, Bhh[5], aNH);

            // activations (biases already inside accumulators)
            // C/D layout: row = quad*4+reg, col = c
            #pragma unroll
            for (int reg = 0; reg < 4; reg++) {
                const int mr = mt * 16 + quad * 4 + reg;
                const bool mv = (mt == 0) | (quad == 0);   // mr < NPB
                float r = sigf(aR[reg]);
                float z = sigf(aZ[reg]);
                float n = tanh_fast(fmaf(r, aNH[reg], aNX[reg]));
                float hn = fmaf(z, hold[mt][reg] - n, n);
                hold[mt][reg] = hn;
                if (mv && jv)
                    an[(jl >> 5) * AH_KGRP + mr * AH_STRIDE + (jl & 31)] = f2fp8(hn);
            }
        }
        __syncthreads();
        xp += xstep;
        // prefetch next step's x A-fragments BEFORE the stores (older in the
        // vmcnt queue -> their wait leaves the stores in flight). Final-step
        // overread lands in workspace slack / Wpk region (values unused).
        axA = *(const v8i*)(xp + xoffA);
        axB = *(const v8i*)(xp + xoffB);
        // global f16 h stores: drain during the next step's compute
        #pragma unroll
        for (int mt = 0; mt < 2; mt++) {
            #pragma unroll
            for (int reg = 0; reg < 4; reg++) {
                const int mr = mt * 16 + quad * 4 + reg;
                const bool mv = (mt == 0) | (quad == 0);
                if (mv && jv) hdt[(long)mr * HROW + jl] = (h16)hold[mt][reg];
            }
        }
        hdt += hstep;
    }
}

// ---------------------------------------------------------------------------
// Word-level attention: one block per sentence. h layout is [s][t][NHP] f16
// -> the 29 KB per (sentence,dir) stage is a contiguous stream.
// tup staged as f16 (28 KB LDS -> 5 blocks/CU). tanh via fast-rcp.
// ---------------------------------------------------------------------------
__global__ __launch_bounds__(256)
void attn_kernel(const h16* __restrict__ hf, const h16* __restrict__ hb,
                 const float* __restrict__ aw, float* __restrict__ H) {
    int s = blockIdx.x;
    int tid = threadIdx.x;
    __shared__ __align__(16) h16 tup[NT][NH];
    __shared__ float sc[NT];
    __shared__ float inv_s;
    // stage hf+hb (16-B vector loads, packed f16 adds; near-linear stream)
    const h16* hfs = hf + (long)s * HROW;
    const h16* hbs = hb + (long)s * HROW;
    for (int i = tid; i < NT * NH / 8; i += 256) {
        int t = i / 25, j8 = (i - t * 25) * 8;
        long off = (long)t * NHP + j8;
        h16x8 f = *(const h16x8*)(hfs + off);
        h16x8 b = *(const h16x8*)(hbs + off);
        *(h16x8*)&tup[t][j8] = f + b;
    }
    __syncthreads();
    int wvv = tid >> 6, lnn = tid & 63;
    for (int t = wvv; t < NT; t += 4) {
        float p = 0.0f;
        for (int j = lnn; j < NH; j += 64) p += tanh_fast((float)tup[t][j]) * aw[j];
        #pragma unroll
        for (int off = 32; off > 0; off >>= 1) p += __shfl_down(p, off, 64);
        if (lnn == 0) sc[t] = p;
    }
    __syncthreads();
    // wave-parallel softmax over T=70 (wave 0)
    if (tid < 64) {
        float v0 = sc[tid];
        float v1 = (tid + 64 < NT) ? sc[tid + 64] : -1e30f;
        float mx = fmaxf(v0, v1);
        #pragma unroll
        for (int off = 32; off > 0; off >>= 1) mx = fmaxf(mx, __shfl_xor(mx, off, 64));
        float e0 = __expf(v0 - mx);
        float e1 = (tid + 64 < NT) ? __expf(v1 - mx) : 0.0f;
        float ssum = e0 + e1;
        #pragma unroll
        for (int off = 32; off > 0; off >>= 1) ssum += __shfl_xor(ssum, off, 64);
        sc[tid] = e0;
        if (tid + 64 < NT) sc[tid + 64] = e1;
        if (tid == 0) inv_s = 1.0f / ssum;
    }
    __syncthreads();
    float inv = inv_s;
    for (int j = tid; j < NH; j += 256) {
        float acc = 0.0f;
        #pragma unroll 7
        for (int t = 0; t < NT; t++) acc += sc[t] * (float)tup[t][j];
        H[s * NH + j] = acc * inv;
    }
}

// ---------------------------------------------------------------------------
// Bag attention + logits + BCE loss.
// ---------------------------------------------------------------------------
__global__ __launch_bounds__(256)
void bag_kernel(const float* __restrict__ H, const int* __restrict__ label,
                const float* __restrict__ sen_a, const float* __restrict__ sen_r,
                const float* __restrict__ rel, const float* __restrict__ sen_d,
                float* __restrict__ out) {
    int b = blockIdx.x;
    int tid = threadIdx.x;
    __shared__ __align__(16) float Hs[NPB][NH];
    __shared__ float e[NPB];
    __shared__ float Sv[NH];
    __shared__ float part[4];
    const float* Hb = H + b * NPB * NH;
    for (int i = tid; i < NPB * NH; i += 256) (&Hs[0][0])[i] = Hb[i];
    __syncthreads();
    int wvv = tid >> 6, lnn = tid & 63;
    for (int n = wvv; n < NPB; n += 4) {
        float p = 0.0f;
        for (int j = lnn; j < NH; j += 64) p += Hs[n][j] * sen_a[j] * sen_r[j];
        #pragma unroll
        for (int off = 32; off > 0; off >>= 1) p += __shfl_down(p, off, 64);
        if (lnn == 0) e[n] = p;
    }
    __syncthreads();
    if (tid == 0) {
        float mx = e[0];
        for (int n = 1; n < NPB; n++) mx = fmaxf(mx, e[n]);
        float sum = 0.0f;
        for (int n = 0; n < NPB; n++) { float v = __expf(e[n] - mx); e[n] = v; sum += v; }
        float inv = 1.0f / sum;
        for (int n = 0; n < NPB; n++) e[n] *= inv;
    }
    __syncthreads();
    for (int j = tid; j < NH; j += 256) {
        float acc = 0.0f;
        #pragma unroll
        for (int n = 0; n < NPB; n++) acc += e[n] * Hs[n][j];
        Sv[j] = acc;
    }
    __syncthreads();
    float bce = 0.0f;
    if (tid < NREL) {
        float acc = 0.0f;
        #pragma unroll 4
        for (int j = 0; j < NH; j++) acc += Sv[j] * rel[tid * NH + j];
        float l = acc + sen_d[tid];
        out[1 + b * NREL + tid] = l;
        float tgt = (label[b] == tid) ? 1.0f : 0.0f;
        bce = fmaxf(l, 0.0f) - l * tgt + log1pf(__expf(-fabsf(l)));
    }
    #pragma unroll
    for (int off = 32; off > 0; off >>= 1) bce += __shfl_down(bce, off, 64);
    if (lnn == 0) part[wvv] = bce;
    __syncthreads();
    if (tid == 0) {
        float tot = (part[0] + part[1] + part[2] + part[3]) * (1.0f / NREL);
        atomicAdd(out, tot);
    }
}

// ---------------------------------------------------------------------------
extern "C" void kernel_launch(void* const* d_in, const int* in_sizes, int n_in,
                              void* d_out, int out_size, void* d_ws, size_t ws_size,
                              hipStream_t stream) {
    const int*   tok   = (const int*)d_in[0];
    const int*   p1    = (const int*)d_in[1];
    const int*   p2    = (const int*)d_in[2];
    const int*   label = (const int*)d_in[3];
    const float* emb   = (const float*)d_in[4];
    const float* pemb  = (const float*)d_in[5];
    const float* WihF  = (const float*)d_in[6];
    const float* WhhF  = (const float*)d_in[7];
    const float* bihF  = (const float*)d_in[8];
    const float* bhhF  = (const float*)d_in[9];
    const float* WihB  = (const float*)d_in[10];
    const float* WhhB  = (const float*)d_in[11];
    const float* bihB  = (const float*)d_in[12];
    const float* bhhB  = (const float*)d_in[13];
    const float* aw    = (const float*)d_in[14];
    const float* sen_a = (const float*)d_in[15];
    const float* sen_r = (const float*)d_in[16];
    const float* rel   = (const float*)d_in[17];
    const float* sen_d = (const float*)d_in[18];

    // workspace layout (all 16B-aligned chunks)
    const long wpk_bytes = 2L * WPK_DIR_BYTES;                 // 479,232
    const long x_bytes   = (long)NT * NS * XSTR + 2048;        // fp8 + OOB slack
    uchar_t* Wpk  = (uchar_t*)d_ws;
    uchar_t* xbuf = Wpk + wpk_bytes;
    float*   Hbuf = (float*)(xbuf + ((x_bytes + 15) & ~15L));  // 2560*200 f32
    h16*     hfb  = (h16*)(Hbuf + NS * NH);                    // [s][t][NHP] f16
    h16*     hbb  = hfb + (long)NS * HROW;

    hipMemsetAsync(d_out, 0, sizeof(float), stream);   // early: overlaps prep
    prep_wpk_kernel<<<(int)((wpk_bytes + 255) / 256), 256, 0, stream>>>(WihF, WhhF, WihB, WhhB, Wpk);
    gather_kernel<<<(NT * NS * 16 + 255) / 256, 256, 0, stream>>>(tok, p1, p2, emb, pemb, xbuf);
    gru_kernel<<<256, 832, 0, stream>>>(xbuf, Wpk, bihF, bhhF, bihB, bhhB, hfb, hbb);
    attn_kernel<<<NS, 256, 0, stream>>>(hfb, hbb, aw, Hbuf);
    bag_kernel<<<NBAG, 256, 0, stream>>>(Hbuf, label, sen_a, sen_r, rel, sen_d, (float*)d_out);
}

// Round 11
// 455.630 us; speedup vs baseline: 1.5033x; 1.5033x over previous
//
#include <hip/hip_runtime.h>
#include <hip/hip_bf16.h>

// Problem constants
#define NS 2560      // B*N sentences
#define NT 70        // tokens per sentence
#define NH 200       // hidden
#define NHP 208      // padded h row stride (16B-aligned rows for f16 stores)
#define NI 60        // input dim (50 + 5 + 5)
#define XSTR 64      // padded x row stride (zeros in [60,64))
#define NREL 100
#define NBAG 128
#define NPB 20       // sentences per bag

#define NTRI 13      // gate triples of 16 (13*16 = 208 >= 200)
#define FR128 2048   // bytes per K=128 fragment (64 lanes x 32)

// h history layout: [s][t][NHP] f16 (R9)
#define HROW ((long)NT * NHP)

// Packed weight layout per dir (K=128 MX fragments, fp8 e4m3, scale=1.0):
//   h-part: [tri 13][kinst 2][seg 3][2048] = 159,744 B  (K=256 padded, k>=200 zero)
//   x-part: [tri 13][seg 3][2048]          =  79,872 B  (K=128 padded, k>=60 zero)
#define WPK_H_BYTES (NTRI * 2 * 3 * FR128)   // 159,744
#define WPK_X_BYTES (NTRI * 3 * FR128)       //  79,872
#define WPK_DIR_BYTES (WPK_H_BYTES + WPK_X_BYTES)

// Ah LDS: [2 buf][8 kgrp][32 row][48]  (row stride 48 = 16B-aligned for b128)
#define AH_STRIDE 48
#define AH_KGRP (32 * AH_STRIDE)     // 1536
#define AH_BUF (8 * AH_KGRP)         // 12288
#define AH_BYTES (2 * AH_BUF)        // 24576

typedef unsigned short ushort_t;
typedef unsigned char uchar_t;
typedef _Float16 h16;
typedef __attribute__((ext_vector_type(4))) float f32x4;
typedef int v2i __attribute__((ext_vector_type(2), aligned(4)));
typedef unsigned int v4u __attribute__((ext_vector_type(4), aligned(16)));
typedef int v8i __attribute__((ext_vector_type(8), aligned(16)));
typedef __attribute__((ext_vector_type(8))) _Float16 h16x8;

// fp8 MX MFMA with unit scales (E8M0 127 = 2^0): plain fp8 GEMM at 2.27x rate
#define MFMA128(A, B, C) \
    __builtin_amdgcn_mfma_scale_f32_16x16x128_f8f6f4((A), (B), (C), 0, 0, 0, 0x7F7F7F7F, 0, 0x7F7F7F7F)

// Fast activations: v_rcp_f32 (1 inst) instead of IEEE division chains
// (R8 mechanism: -130 us). Error invisible under fp8 quantization.
__device__ __forceinline__ float rcpf(float x) { return __builtin_amdgcn_rcpf(x); }
__device__ __forceinline__ float sigf(float x) { return rcpf(1.0f + __expf(-x)); }
__device__ __forceinline__ float tanh_fast(float x) {
    float e = __expf(2.0f * x);
    return 1.0f - 2.0f * rcpf(e + 1.0f);
}

// fp8 e4m3 (OCP on gfx950) encode, RTNE
__device__ __forceinline__ uchar_t f2fp8(float f) {
#if __has_builtin(__builtin_amdgcn_cvt_pk_fp8_f32)
    int p = __builtin_amdgcn_cvt_pk_fp8_f32(f, f, 0, false);
    return (uchar_t)(p & 0xff);
#else
    unsigned u = __float_as_uint(f);
    unsigned s = (u >> 24) & 0x80u;
    float a = fabsf(f);
    if (a >= 448.0f) return (uchar_t)(s | 0x7E);
    if (a < 0.015625f) {
        int q = (int)rintf(a * 512.0f);
        return (uchar_t)(s | (unsigned)q);
    }
    unsigned au = __float_as_uint(a);
    int e = (int)(au >> 23) - 127;
    unsigned m = au & 0x7fffffu;
    unsigned keep = m >> 20;
    unsigned rnd = (m >> 19) & 1u;
    unsigned sticky = (m & 0x7ffffu) ? 1u : 0u;
    keep += (rnd & (sticky | (keep & 1u)));
    int ee = e + 7;
    if (keep == 8u) { keep = 0u; ee += 1; }
    if (ee >= 16) return (uchar_t)(s | 0x7E);
    return (uchar_t)(s | ((unsigned)ee << 3) | keep);
#endif
}

// ---------------------------------------------------------------------------
// Pack weights into K=128 MFMA B-fragment order, fp8 e4m3, zero-padded.
// B-frag for 16x16x128 f8f6f4: lane ln holds col n=(ln&15), k=(ln>>4)*32+j,
// j=0..31 (one contiguous 32-k MX block per lane). n -> gate g = seg*200+16*tri+n.
// ---------------------------------------------------------------------------
__global__ void prep_wpk_kernel(const float* __restrict__ WihF, const float* __restrict__ WhhF,
                                const float* __restrict__ WihB, const float* __restrict__ WhhB,
                                uchar_t* __restrict__ Wpk) {
    int idx = blockIdx.x * 256 + threadIdx.x;
    const int total = 2 * WPK_DIR_BYTES;
    if (idx >= total) return;
    int d = idx / WPK_DIR_BYTES;
    int r = idx - d * WPK_DIR_BYTES;
    int tri, kinst, seg, e;
    bool isX;
    if (r < WPK_H_BYTES) {
        tri = r / 12288;
        int r2 = r % 12288;
        kinst = r2 / 6144;
        int r3 = r2 % 6144;
        seg = r3 / 2048;
        e = r3 % 2048;
        isX = false;
    } else {
        int r2 = r - WPK_H_BYTES;
        tri = r2 / 6144;
        int r3 = r2 % 6144;
        seg = r3 / 2048;
        e = r3 % 2048;
        kinst = 0;
        isX = true;
    }
    int ln = e >> 5;
    int j = e & 31;
    const float* Wih = d ? WihB : WihF;
    const float* Whh = d ? WhhB : WhhF;
    int gl = 16 * tri + (ln & 15);
    int k = kinst * 128 + ((ln >> 4) << 5) + j;
    float v = 0.0f;
    if (gl < NH) {
        int g = seg * NH + gl;
        if (isX) { if (k < NI) v = Wih[g * NI + k]; }
        else     { if (k < NH) v = Whh[g * NH + k]; }
    }
    Wpk[idx] = f2fp8(v);
}

// ---------------------------------------------------------------------------
// Gather x[t][s][d] = concat(word_emb, pos1_emb, pos2_emb), fp8,
// [70][2560][XSTR=64] with zeros in d in [60,64).
// ---------------------------------------------------------------------------
__global__ void gather_kernel(const int* __restrict__ tok, const int* __restrict__ p1,
                              const int* __restrict__ p2, const float* __restrict__ emb,
                              const float* __restrict__ pemb, uchar_t* __restrict__ x) {
    int idx = blockIdx.x * 256 + threadIdx.x;
    if (idx >= NT * NS * 16) return;
    int chunk = idx & 15;
    int st = idx >> 4;
    int s = st % NS;
    int t = st / NS;
    int o = s * NT + t;
    int d4 = chunk * 4;
    unsigned out = 0;
    #pragma unroll
    for (int e = 0; e < 4; e++) {
        int d = d4 + e;
        float v = 0.0f;
        if (d < 50)      v = emb[(long)tok[o] * 50 + d];
        else if (d < 55) v = pemb[p1[o] * 5 + (d - 50)];
        else if (d < 60) v = pemb[p2[o] * 5 + (d - 55)];
        out |= ((unsigned)f2fp8(v)) << (8 * e);
    }
    *(unsigned*)(x + ((long)t * NS + s) * XSTR + d4) = out;
}

// ---------------------------------------------------------------------------
// MX-MFMA GRU. 256 blocks (128 groups x 2 dirs) = 1 block/CU, 832 thr = 13
// waves. Wave w owns gate-triple w (gates [16w,16w+16) of r,z,n).
// This is the verified R9 structure (gru 236 us measured):
//  - K=128 scaled MFMA (scale=1.0), 18 MFMA/wave/step, 3-deep acc chains
//  - B-fragments asm-pinned in registers (R5/R6 rematerialization lesson)
//  - fast-rcp activations (R8: -130 us)
//  - x loads at step top; h-MFMAs first so ax's global latency hides under
//    them (R10 taught: reordering ax-first EXPOSES that latency)
//  - NO cross-step register prefetch (R10: +16 VGPR -> scratch spill)
//  - biases added in epilogue VALU (bias-in-C regressed in 2 bundles)
//  - h stores [s][t][NHP] f16 AFTER the barrier (drain in next step's shadow)
// ---------------------------------------------------------------------------
__global__ __launch_bounds__(832, 4)
void gru_kernel(const uchar_t* __restrict__ x, const uchar_t* __restrict__ Wpk,
                const float* __restrict__ bihF, const float* __restrict__ bhhF,
                const float* __restrict__ bihB, const float* __restrict__ bhhB,
                h16* __restrict__ hfo, h16* __restrict__ hbo) {
    __shared__ __align__(16) uchar_t Ah[AH_BYTES];   // [2][8][32][48] fp8 A(h) dbuf

    const int dir = blockIdx.x >> 7;
    const int s0 = (blockIdx.x & 127) * NPB;
    const int tid = threadIdx.x;
    const int wv = tid >> 6, ln = tid & 63;
    const int c = ln & 15, quad = ln >> 4;
    const int jl = 16 * wv + c;
    const bool jv = jl < NH;

    const float* bih = dir ? bihB : bihF;
    const float* bhh = dir ? bhhB : bhhF;
    const uchar_t* wdir = Wpk + (long)dir * WPK_DIR_BYTES;
    h16* hd = dir ? hbo : hfo;

    const float br  = jv ? bih[jl] + bhh[jl] : 0.0f;
    const float bz  = jv ? bih[NH + jl] + bhh[NH + jl] : 0.0f;
    const float bnx = jv ? bih[2 * NH + jl] : 0.0f;
    const float bnh = jv ? bhh[2 * NH + jl] : 0.0f;

    // B fragments: loop-invariant -> registers, PINNED (asm-opaque so the
    // allocator cannot rematerialize them as per-step loads).
    v8i Bhh[6];
    v8i Bx[3];
    {
        const uchar_t* wh = wdir + wv * (6 * FR128) + ln * 32;
        #pragma unroll
        for (int i = 0; i < 6; i++) Bhh[i] = *(const v8i*)(wh + i * FR128);
        const uchar_t* wx = wdir + WPK_H_BYTES + wv * (3 * FR128) + ln * 32;
        #pragma unroll
        for (int i = 0; i < 3; i++) Bx[i] = *(const v8i*)(wx + i * FR128);
        #pragma unroll
        for (int i = 0; i < 6; i++) {
            #pragma unroll
            for (int j = 0; j < 8; j++) {
                int tmp = Bhh[i][j];
                asm volatile("" : "+v"(tmp));
                Bhh[i][j] = tmp;
            }
        }
        #pragma unroll
        for (int i = 0; i < 3; i++) {
            #pragma unroll
            for (int j = 0; j < 8; j++) {
                int tmp = Bx[i][j];
                asm volatile("" : "+v"(tmp));
                Bx[i][j] = tmp;
            }
        }
    }

    // zero Ah (h0 = 0; pad rows 20..31, cols 200..207, k 208..255 stay zero)
    for (int i = tid; i < AH_BYTES / 4; i += 832) ((unsigned*)Ah)[i] = 0u;
    __syncthreads();

    float hold[2][4] = {};   // [mt][reg], f32 carry (full precision recurrence)

    const long xstep = dir ? -(long)NS * XSTR : (long)NS * XSTR;
    const long hstep = dir ? -(long)NHP : (long)NHP;   // per-t step in [s][t] layout
    const uchar_t* xp = x + ((long)(dir ? NT - 1 : 0) * NS + s0) * XSTR;
    h16* hdt = hd + (long)s0 * HROW + (long)(dir ? NT - 1 : 0) * NHP;
    const f32x4 vz = {0.0f, 0.0f, 0.0f, 0.0f};

    for (int t = 0; t < NT; t++) {
        const int cur = t & 1, nxt = cur ^ 1;
        const uchar_t* ac = Ah + cur * AH_BUF;
        uchar_t* an = Ah + nxt * AH_BUF;

        #pragma unroll
        for (int mt = 0; mt < 2; mt++) {
            const int row = mt * 16 + c;
            // x A-fragment from global (invalid-range rows multiply zero-B;
            // fp8 garbage is never NaN since the encoder saturates)
            v8i ax = *(const v8i*)(xp + (long)row * XSTR + quad * 32);
            // h A-fragments from LDS: kinst0 -> kgrp quad, kinst1 -> kgrp 4+quad
            v8i a0 = *(const v8i*)(ac + quad * AH_KGRP + row * AH_STRIDE);
            v8i a1 = *(const v8i*)(ac + (4 + quad) * AH_KGRP + row * AH_STRIDE);

            f32x4 aR  = MFMA128(a0, Bhh[0], vz);
            f32x4 aZ  = MFMA128(a0, Bhh[1], vz);
            f32x4 aNH = MFMA128(a0, Bhh[2], vz);
            aR  = MFMA128(a1, Bhh[3], aR);
            aZ  = MFMA128(a1, Bhh[4], aZ);
            aNH = MFMA128(a1, Bhh[5], aNH);
            aR  = MFMA128(ax, Bx[0], aR);
            aZ  = MFMA128(ax, Bx[1], aZ);
            f32x4 aNX = MFMA128(ax, Bx[2], vz);

            // activations + h update; C/D layout: row = quad*4+reg, col = c
            #pragma unroll
            for (int reg = 0; reg < 4; reg++) {
                const int mr = mt * 16 + quad * 4 + reg;
                const bool mv = (mt == 0) | (quad == 0);   // mr < NPB
                float r = sigf(aR[reg] + br);
                float z = sigf(aZ[reg] + bz);
                float n = tanh_fast(fmaf(r, aNH[reg] + bnh, aNX[reg] + bnx));
                float hn = fmaf(z, hold[mt][reg] - n, n);
                hold[mt][reg] = hn;
                if (mv && jv)
                    an[(jl >> 5) * AH_KGRP + mr * AH_STRIDE + (jl & 31)] = f2fp8(hn);
            }
        }
        __syncthreads();
        // global f16 h stores AFTER the barrier ([s][t] layout: 20 coalesced
        // 32B-segment rows; drains during the next step's compute)
        #pragma unroll
        for (int mt = 0; mt < 2; mt++) {
            #pragma unroll
            for (int reg = 0; reg < 4; reg++) {
                const int mr = mt * 16 + quad * 4 + reg;
                const bool mv = (mt == 0) | (quad == 0);
                if (mv && jv) hdt[(long)mr * HROW + jl] = (h16)hold[mt][reg];
            }
        }
        xp += xstep;
        hdt += hstep;
    }
}

// ---------------------------------------------------------------------------
// Word-level attention: one block per sentence. h layout is [s][t][NHP] f16
// -> the 29 KB per (sentence,dir) stage is a contiguous stream.
// tup staged as f16 (28 KB LDS -> 5 blocks/CU). tanh via fast-rcp.
// ---------------------------------------------------------------------------
__global__ __launch_bounds__(256)
void attn_kernel(const h16* __restrict__ hf, const h16* __restrict__ hb,
                 const float* __restrict__ aw, float* __restrict__ H) {
    int s = blockIdx.x;
    int tid = threadIdx.x;
    __shared__ __align__(16) h16 tup[NT][NH];
    __shared__ float sc[NT];
    __shared__ float inv_s;
    // stage hf+hb (16-B vector loads, packed f16 adds; near-linear stream)
    const h16* hfs = hf + (long)s * HROW;
    const h16* hbs = hb + (long)s * HROW;
    for (int i = tid; i < NT * NH / 8; i += 256) {
        int t = i / 25, j8 = (i - t * 25) * 8;
        long off = (long)t * NHP + j8;
        h16x8 f = *(const h16x8*)(hfs + off);
        h16x8 b = *(const h16x8*)(hbs + off);
        *(h16x8*)&tup[t][j8] = f + b;
    }
    __syncthreads();
    int wvv = tid >> 6, lnn = tid & 63;
    for (int t = wvv; t < NT; t += 4) {
        float p = 0.0f;
        for (int j = lnn; j < NH; j += 64) p += tanh_fast((float)tup[t][j]) * aw[j];
        #pragma unroll
        for (int off = 32; off > 0; off >>= 1) p += __shfl_down(p, off, 64);
        if (lnn == 0) sc[t] = p;
    }
    __syncthreads();
    // wave-parallel softmax over T=70 (wave 0)
    if (tid < 64) {
        float v0 = sc[tid];
        float v1 = (tid + 64 < NT) ? sc[tid + 64] : -1e30f;
        float mx = fmaxf(v0, v1);
        #pragma unroll
        for (int off = 32; off > 0; off >>= 1) mx = fmaxf(mx, __shfl_xor(mx, off, 64));
        float e0 = __expf(v0 - mx);
        float e1 = (tid + 64 < NT) ? __expf(v1 - mx) : 0.0f;
        float ssum = e0 + e1;
        #pragma unroll
        for (int off = 32; off > 0; off >>= 1) ssum += __shfl_xor(ssum, off, 64);
        sc[tid] = e0;
        if (tid + 64 < NT) sc[tid + 64] = e1;
        if (tid == 0) inv_s = 1.0f / ssum;
    }
    __syncthreads();
    float inv = inv_s;
    for (int j = tid; j < NH; j += 256) {
        float acc = 0.0f;
        #pragma unroll 7
        for (int t = 0; t < NT; t++) acc += sc[t] * (float)tup[t][j];
        H[s * NH + j] = acc * inv;
    }
}

// ---------------------------------------------------------------------------
// Bag attention + logits + BCE loss.
// ---------------------------------------------------------------------------
__global__ __launch_bounds__(256)
void bag_kernel(const float* __restrict__ H, const int* __restrict__ label,
                const float* __restrict__ sen_a, const float* __restrict__ sen_r,
                const float* __restrict__ rel, const float* __restrict__ sen_d,
                float* __restrict__ out) {
    int b = blockIdx.x;
    int tid = threadIdx.x;
    __shared__ __align__(16) float Hs[NPB][NH];
    __shared__ float e[NPB];
    __shared__ float Sv[NH];
    __shared__ float part[4];
    const float* Hb = H + b * NPB * NH;
    for (int i = tid; i < NPB * NH; i += 256) (&Hs[0][0])[i] = Hb[i];
    __syncthreads();
    int wvv = tid >> 6, lnn = tid & 63;
    for (int n = wvv; n < NPB; n += 4) {
        float p = 0.0f;
        for (int j = lnn; j < NH; j += 64) p += Hs[n][j] * sen_a[j] * sen_r[j];
        #pragma unroll
        for (int off = 32; off > 0; off >>= 1) p += __shfl_down(p, off, 64);
        if (lnn == 0) e[n] = p;
    }
    __syncthreads();
    if (tid == 0) {
        float mx = e[0];
        for (int n = 1; n < NPB; n++) mx = fmaxf(mx, e[n]);
        float sum = 0.0f;
        for (int n = 0; n < NPB; n++) { float v = __expf(e[n] - mx); e[n] = v; sum += v; }
        float inv = 1.0f / sum;
        for (int n = 0; n < NPB; n++) e[n] *= inv;
    }
    __syncthreads();
    for (int j = tid; j < NH; j += 256) {
        float acc = 0.0f;
        #pragma unroll
        for (int n = 0; n < NPB; n++) acc += e[n] * Hs[n][j];
        Sv[j] = acc;
    }
    __syncthreads();
    float bce = 0.0f;
    if (tid < NREL) {
        float acc = 0.0f;
        #pragma unroll 4
        for (int j = 0; j < NH; j++) acc += Sv[j] * rel[tid * NH + j];
        float l = acc + sen_d[tid];
        out[1 + b * NREL + tid] = l;
        float tgt = (label[b] == tid) ? 1.0f : 0.0f;
        bce = fmaxf(l, 0.0f) - l * tgt + log1pf(__expf(-fabsf(l)));
    }
    #pragma unroll
    for (int off = 32; off > 0; off >>= 1) bce += __shfl_down(bce, off, 64);
    if (lnn == 0) part[wvv] = bce;
    __syncthreads();
    if (tid == 0) {
        float tot = (part[0] + part[1] + part[2] + part[3]) * (1.0f / NREL);
        atomicAdd(out, tot);
    }
}

// ---------------------------------------------------------------------------
extern "C" void kernel_launch(void* const* d_in, const int* in_sizes, int n_in,
                              void* d_out, int out_size, void* d_ws, size_t ws_size,
                              hipStream_t stream) {
    const int*   tok   = (const int*)d_in[0];
    const int*   p1    = (const int*)d_in[1];
    const int*   p2    = (const int*)d_in[2];
    const int*   label = (const int*)d_in[3];
    const float* emb   = (const float*)d_in[4];
    const float* pemb  = (const float*)d_in[5];
    const float* WihF  = (const float*)d_in[6];
    const float* WhhF  = (const float*)d_in[7];
    const float* bihF  = (const float*)d_in[8];
    const float* bhhF  = (const float*)d_in[9];
    const float* WihB  = (const float*)d_in[10];
    const float* WhhB  = (const float*)d_in[11];
    const float* bihB  = (const float*)d_in[12];
    const float* bhhB  = (const float*)d_in[13];
    const float* aw    = (const float*)d_in[14];
    const float* sen_a = (const float*)d_in[15];
    const float* sen_r = (const float*)d_in[16];
    const float* rel   = (const float*)d_in[17];
    const float* sen_d = (const float*)d_in[18];

    // workspace layout (all 16B-aligned chunks)
    const long wpk_bytes = 2L * WPK_DIR_BYTES;                 // 479,232
    const long x_bytes   = (long)NT * NS * XSTR + 2048;        // fp8 + OOB slack
    uchar_t* Wpk  = (uchar_t*)d_ws;
    uchar_t* xbuf = Wpk + wpk_bytes;
    float*   Hbuf = (float*)(xbuf + ((x_bytes + 15) & ~15L));  // 2560*200 f32
    h16*     hfb  = (h16*)(Hbuf + NS * NH);                    // [s][t][NHP] f16
    h16*     hbb  = hfb + (long)NS * HROW;

    hipMemsetAsync(d_out, 0, sizeof(float), stream);   // early: overlaps prep
    prep_wpk_kernel<<<(int)((wpk_bytes + 255) / 256), 256, 0, stream>>>(WihF, WhhF, WihB, WhhB, Wpk);
    gather_kernel<<<(NT * NS * 16 + 255) / 256, 256, 0, stream>>>(tok, p1, p2, emb, pemb, xbuf);
    gru_kernel<<<256, 832, 0, stream>>>(xbuf, Wpk, bihF, bhhF, bihB, bhhB, hfb, hbb);
    attn_kernel<<<NS, 256, 0, stream>>>(hfb, hbb, aw, Hbuf);
    bag_kernel<<<NBAG, 256, 0, stream>>>(Hbuf, label, sen_a, sen_r, rel, sen_d, (float*)d_out);
}

// Round 12
// 455.215 us; speedup vs baseline: 1.5047x; 1.0009x over previous
//
#include <hip/hip_runtime.h>
#include <hip/hip_bf16.h>

// Problem constants
#define NS 2560      // B*N sentences
#define NT 70        // tokens per sentence
#define NH 200       // hidden
#define NHP 208      // padded h row stride (16B-aligned rows for f16 stores)
#define NI 60        // input dim (50 + 5 + 5)
#define XSTR 64      // padded x row stride (zeros in [60,64))
#define NREL 100
#define NBAG 128
#define NPB 20       // sentences per bag

#define NTRI 13      // gate triples of 16 (13*16 = 208 >= 200)
#define FR128 2048   // bytes per K=128 fragment (64 lanes x 32)

// h history layout: [s][t][NHP] f16 (R9)
#define HROW ((long)NT * NHP)

// Packed weight layout per dir (K=128 MX fragments, fp8 e4m3, scale=1.0):
//   h-part: [tri 13][kinst 2][seg 3][2048] = 159,744 B  (K=256 padded, k>=200 zero)
//   x-part: [tri 13][seg 3][2048]          =  79,872 B  (K=128 padded, k>=60 zero)
#define WPK_H_BYTES (NTRI * 2 * 3 * FR128)   // 159,744
#define WPK_X_BYTES (NTRI * 3 * FR128)       //  79,872
#define WPK_DIR_BYTES (WPK_H_BYTES + WPK_X_BYTES)

// Fused preprocessing grid split (R12): prep and gather are independent;
// fusing removes the inter-kernel serialization (prep's compute hides in
// gather's BW-idle issue slots).
#define PREP_BLOCKS ((2 * WPK_DIR_BYTES + 255) / 256)          // 1872
#define GATHER_BLOCKS ((NT * NS * 16 + 255) / 256)             // 11200

// Ah LDS: [2 buf][8 kgrp][32 row][48]  (row stride 48 = 16B-aligned for b128)
#define AH_STRIDE 48
#define AH_KGRP (32 * AH_STRIDE)     // 1536
#define AH_BUF (8 * AH_KGRP)         // 12288
#define AH_BYTES (2 * AH_BUF)        // 24576

typedef unsigned short ushort_t;
typedef unsigned char uchar_t;
typedef _Float16 h16;
typedef __attribute__((ext_vector_type(4))) float f32x4;
typedef int v2i __attribute__((ext_vector_type(2), aligned(4)));
typedef unsigned int v4u __attribute__((ext_vector_type(4), aligned(16)));
typedef int v8i __attribute__((ext_vector_type(8), aligned(16)));
typedef __attribute__((ext_vector_type(8))) _Float16 h16x8;

// fp8 MX MFMA with unit scales (E8M0 127 = 2^0): plain fp8 GEMM at 2.27x rate
#define MFMA128(A, B, C) \
    __builtin_amdgcn_mfma_scale_f32_16x16x128_f8f6f4((A), (B), (C), 0, 0, 0, 0x7F7F7F7F, 0, 0x7F7F7F7F)

// Fast activations: v_rcp_f32 (1 inst) instead of IEEE division chains
// (R8 mechanism: -130 us). Error invisible under fp8 quantization.
__device__ __forceinline__ float rcpf(float x) { return __builtin_amdgcn_rcpf(x); }
__device__ __forceinline__ float sigf(float x) { return rcpf(1.0f + __expf(-x)); }
__device__ __forceinline__ float tanh_fast(float x) {
    float e = __expf(2.0f * x);
    return 1.0f - 2.0f * rcpf(e + 1.0f);
}

// fp8 e4m3 (OCP on gfx950) encode, RTNE
__device__ __forceinline__ uchar_t f2fp8(float f) {
#if __has_builtin(__builtin_amdgcn_cvt_pk_fp8_f32)
    int p = __builtin_amdgcn_cvt_pk_fp8_f32(f, f, 0, false);
    return (uchar_t)(p & 0xff);
#else
    unsigned u = __float_as_uint(f);
    unsigned s = (u >> 24) & 0x80u;
    float a = fabsf(f);
    if (a >= 448.0f) return (uchar_t)(s | 0x7E);
    if (a < 0.015625f) {
        int q = (int)rintf(a * 512.0f);
        return (uchar_t)(s | (unsigned)q);
    }
    unsigned au = __float_as_uint(a);
    int e = (int)(au >> 23) - 127;
    unsigned m = au & 0x7fffffu;
    unsigned keep = m >> 20;
    unsigned rnd = (m >> 19) & 1u;
    unsigned sticky = (m & 0x7ffffu) ? 1u : 0u;
    keep += (rnd & (sticky | (keep & 1u)));
    int ee = e + 7;
    if (keep == 8u) { keep = 0u; ee += 1; }
    if (ee >= 16) return (uchar_t)(s | 0x7E);
    return (uchar_t)(s | ((unsigned)ee << 3) | keep);
#endif
}

// ---------------------------------------------------------------------------
// FUSED preprocessing (R12): blocks [0,PREP_BLOCKS) pack weights into K=128
// MFMA B-fragment order; blocks [PREP_BLOCKS,..) gather x. The two tasks are
// independent and both precede gru; fusing removes their serialization.
// B-frag for 16x16x128 f8f6f4: lane ln holds col n=(ln&15), k=(ln>>4)*32+j,
// j=0..31 (one contiguous 32-k MX block per lane). n -> gate g = seg*200+16*tri+n.
// x[t][s][d] = concat(word_emb, pos1_emb, pos2_emb), fp8, [70][2560][XSTR=64],
// zeros in d in [60,64).
// ---------------------------------------------------------------------------
__global__ void prep_gather_kernel(const float* __restrict__ WihF, const float* __restrict__ WhhF,
                                   const float* __restrict__ WihB, const float* __restrict__ WhhB,
                                   uchar_t* __restrict__ Wpk,
                                   const int* __restrict__ tok, const int* __restrict__ p1,
                                   const int* __restrict__ p2, const float* __restrict__ emb,
                                   const float* __restrict__ pemb, uchar_t* __restrict__ x) {
    if (blockIdx.x < PREP_BLOCKS) {
        // ---- weight-pack path ----
        int idx = blockIdx.x * 256 + threadIdx.x;
        const int total = 2 * WPK_DIR_BYTES;
        if (idx >= total) return;
        int d = idx / WPK_DIR_BYTES;
        int r = idx - d * WPK_DIR_BYTES;
        int tri, kinst, seg, e;
        bool isX;
        if (r < WPK_H_BYTES) {
            tri = r / 12288;
            int r2 = r % 12288;
            kinst = r2 / 6144;
            int r3 = r2 % 6144;
            seg = r3 / 2048;
            e = r3 % 2048;
            isX = false;
        } else {
            int r2 = r - WPK_H_BYTES;
            tri = r2 / 6144;
            int r3 = r2 % 6144;
            seg = r3 / 2048;
            e = r3 % 2048;
            kinst = 0;
            isX = true;
        }
        int ln = e >> 5;
        int j = e & 31;
        const float* Wih = d ? WihB : WihF;
        const float* Whh = d ? WhhB : WhhF;
        int gl = 16 * tri + (ln & 15);
        int k = kinst * 128 + ((ln >> 4) << 5) + j;
        float v = 0.0f;
        if (gl < NH) {
            int g = seg * NH + gl;
            if (isX) { if (k < NI) v = Wih[g * NI + k]; }
            else     { if (k < NH) v = Whh[g * NH + k]; }
        }
        Wpk[idx] = f2fp8(v);
    } else {
        // ---- x-gather path ----
        int idx = (blockIdx.x - PREP_BLOCKS) * 256 + threadIdx.x;
        if (idx >= NT * NS * 16) return;
        int chunk = idx & 15;
        int st = idx >> 4;
        int s = st % NS;
        int t = st / NS;
        int o = s * NT + t;
        int d4 = chunk * 4;
        unsigned out = 0;
        #pragma unroll
        for (int e = 0; e < 4; e++) {
            int d = d4 + e;
            float v = 0.0f;
            if (d < 50)      v = emb[(long)tok[o] * 50 + d];
            else if (d < 55) v = pemb[p1[o] * 5 + (d - 50)];
            else if (d < 60) v = pemb[p2[o] * 5 + (d - 55)];
            out |= ((unsigned)f2fp8(v)) << (8 * e);
        }
        *(unsigned*)(x + ((long)t * NS + s) * XSTR + d4) = out;
    }
}

// ---------------------------------------------------------------------------
// MX-MFMA GRU. 256 blocks (128 groups x 2 dirs) = 1 block/CU, 832 thr = 13
// waves. Wave w owns gate-triple w (gates [16w,16w+16) of r,z,n).
// Verified R9 structure (gru ~234 us measured):
//  - K=128 scaled MFMA (scale=1.0), 18 MFMA/wave/step, 3-deep acc chains
//  - B-fragments asm-pinned in registers (R5/R6 rematerialization lesson)
//  - fast-rcp activations (R8: -130 us)
//  - x loads at step top; h-MFMAs first so ax's global latency hides under
//    them (R10: ax-first EXPOSES that latency)
//  - NO cross-step register prefetch (R10: +16 VGPR -> scratch spill)
//  - biases added in epilogue VALU (bias-in-C regressed in 2 bundles)
//  - h stores [s][t][NHP] f16 AFTER the barrier (drain in next step's shadow)
// ---------------------------------------------------------------------------
__global__ __launch_bounds__(832, 4)
void gru_kernel(const uchar_t* __restrict__ x, const uchar_t* __restrict__ Wpk,
                const float* __restrict__ bihF, const float* __restrict__ bhhF,
                const float* __restrict__ bihB, const float* __restrict__ bhhB,
                h16* __restrict__ hfo, h16* __restrict__ hbo) {
    __shared__ __align__(16) uchar_t Ah[AH_BYTES];   // [2][8][32][48] fp8 A(h) dbuf

    const int dir = blockIdx.x >> 7;
    const int s0 = (blockIdx.x & 127) * NPB;
    const int tid = threadIdx.x;
    const int wv = tid >> 6, ln = tid & 63;
    const int c = ln & 15, quad = ln >> 4;
    const int jl = 16 * wv + c;
    const bool jv = jl < NH;

    const float* bih = dir ? bihB : bihF;
    const float* bhh = dir ? bhhB : bhhF;
    const uchar_t* wdir = Wpk + (long)dir * WPK_DIR_BYTES;
    h16* hd = dir ? hbo : hfo;

    const float br  = jv ? bih[jl] + bhh[jl] : 0.0f;
    const float bz  = jv ? bih[NH + jl] + bhh[NH + jl] : 0.0f;
    const float bnx = jv ? bih[2 * NH + jl] : 0.0f;
    const float bnh = jv ? bhh[2 * NH + jl] : 0.0f;

    // B fragments: loop-invariant -> registers, PINNED (asm-opaque so the
    // allocator cannot rematerialize them as per-step loads).
    v8i Bhh[6];
    v8i Bx[3];
    {
        const uchar_t* wh = wdir + wv * (6 * FR128) + ln * 32;
        #pragma unroll
        for (int i = 0; i < 6; i++) Bhh[i] = *(const v8i*)(wh + i * FR128);
        const uchar_t* wx = wdir + WPK_H_BYTES + wv * (3 * FR128) + ln * 32;
        #pragma unroll
        for (int i = 0; i < 3; i++) Bx[i] = *(const v8i*)(wx + i * FR128);
        #pragma unroll
        for (int i = 0; i < 6; i++) {
            #pragma unroll
            for (int j = 0; j < 8; j++) {
                int tmp = Bhh[i][j];
                asm volatile("" : "+v"(tmp));
                Bhh[i][j] = tmp;
            }
        }
        #pragma unroll
        for (int i = 0; i < 3; i++) {
            #pragma unroll
            for (int j = 0; j < 8; j++) {
                int tmp = Bx[i][j];
                asm volatile("" : "+v"(tmp));
                Bx[i][j] = tmp;
            }
        }
    }

    // zero Ah (h0 = 0; pad rows 20..31, cols 200..207, k 208..255 stay zero)
    for (int i = tid; i < AH_BYTES / 4; i += 832) ((unsigned*)Ah)[i] = 0u;
    __syncthreads();

    float hold[2][4] = {};   // [mt][reg], f32 carry (full precision recurrence)

    const long xstep = dir ? -(long)NS * XSTR : (long)NS * XSTR;
    const long hstep = dir ? -(long)NHP : (long)NHP;   // per-t step in [s][t] layout
    const uchar_t* xp = x + ((long)(dir ? NT - 1 : 0) * NS + s0) * XSTR;
    h16* hdt = hd + (long)s0 * HROW + (long)(dir ? NT - 1 : 0) * NHP;
    const f32x4 vz = {0.0f, 0.0f, 0.0f, 0.0f};

    for (int t = 0; t < NT; t++) {
        const int cur = t & 1, nxt = cur ^ 1;
        const uchar_t* ac = Ah + cur * AH_BUF;
        uchar_t* an = Ah + nxt * AH_BUF;

        #pragma unroll
        for (int mt = 0; mt < 2; mt++) {
            const int row = mt * 16 + c;
            // x A-fragment from global (invalid-range rows multiply zero-B;
            // fp8 garbage is never NaN since the encoder saturates)
            v8i ax = *(const v8i*)(xp + (long)row * XSTR + quad * 32);
            // h A-fragments from LDS: kinst0 -> kgrp quad, kinst1 -> kgrp 4+quad
            v8i a0 = *(const v8i*)(ac + quad * AH_KGRP + row * AH_STRIDE);
            v8i a1 = *(const v8i*)(ac + (4 + quad) * AH_KGRP + row * AH_STRIDE);

            f32x4 aR  = MFMA128(a0, Bhh[0], vz);
            f32x4 aZ  = MFMA128(a0, Bhh[1], vz);
            f32x4 aNH = MFMA128(a0, Bhh[2], vz);
            aR  = MFMA128(a1, Bhh[3], aR);
            aZ  = MFMA128(a1, Bhh[4], aZ);
            aNH = MFMA128(a1, Bhh[5], aNH);
            aR  = MFMA128(ax, Bx[0], aR);
            aZ  = MFMA128(ax, Bx[1], aZ);
            f32x4 aNX = MFMA128(ax, Bx[2], vz);

            // activations + h update; C/D layout: row = quad*4+reg, col = c
            #pragma unroll
            for (int reg = 0; reg < 4; reg++) {
                const int mr = mt * 16 + quad * 4 + reg;
                const bool mv = (mt == 0) | (quad == 0);   // mr < NPB
                float r = sigf(aR[reg] + br);
                float z = sigf(aZ[reg] + bz);
                float n = tanh_fast(fmaf(r, aNH[reg] + bnh, aNX[reg] + bnx));
                float hn = fmaf(z, hold[mt][reg] - n, n);
                hold[mt][reg] = hn;
                if (mv && jv)
                    an[(jl >> 5) * AH_KGRP + mr * AH_STRIDE + (jl & 31)] = f2fp8(hn);
            }
        }
        __syncthreads();
        // global f16 h stores AFTER the barrier ([s][t] layout: 20 coalesced
        // 32B-segment rows; drains during the next step's compute)
        #pragma unroll
        for (int mt = 0; mt < 2; mt++) {
            #pragma unroll
            for (int reg = 0; reg < 4; reg++) {
                const int mr = mt * 16 + quad * 4 + reg;
                const bool mv = (mt == 0) | (quad == 0);
                if (mv && jv) hdt[(long)mr * HROW + jl] = (h16)hold[mt][reg];
            }
        }
        xp += xstep;
        hdt += hstep;
    }
}

// ---------------------------------------------------------------------------
// Word-level attention: one block per sentence. h layout is [s][t][NHP] f16
// -> the 29 KB per (sentence,dir) stage is a contiguous stream.
// tup staged as f16 (28 KB LDS -> 5 blocks/CU). tanh via fast-rcp.
// ---------------------------------------------------------------------------
__global__ __launch_bounds__(256)
void attn_kernel(const h16* __restrict__ hf, const h16* __restrict__ hb,
                 const float* __restrict__ aw, float* __restrict__ H) {
    int s = blockIdx.x;
    int tid = threadIdx.x;
    __shared__ __align__(16) h16 tup[NT][NH];
    __shared__ float sc[NT];
    __shared__ float inv_s;
    // stage hf+hb (16-B vector loads, packed f16 adds; near-linear stream)
    const h16* hfs = hf + (long)s * HROW;
    const h16* hbs = hb + (long)s * HROW;
    for (int i = tid; i < NT * NH / 8; i += 256) {
        int t = i / 25, j8 = (i - t * 25) * 8;
        long off = (long)t * NHP + j8;
        h16x8 f = *(const h16x8*)(hfs + off);
        h16x8 b = *(const h16x8*)(hbs + off);
        *(h16x8*)&tup[t][j8] = f + b;
    }
    __syncthreads();
    int wvv = tid >> 6, lnn = tid & 63;
    for (int t = wvv; t < NT; t += 4) {
        float p = 0.0f;
        for (int j = lnn; j < NH; j += 64) p += tanh_fast((float)tup[t][j]) * aw[j];
        #pragma unroll
        for (int off = 32; off > 0; off >>= 1) p += __shfl_down(p, off, 64);
        if (lnn == 0) sc[t] = p;
    }
    __syncthreads();
    // wave-parallel softmax over T=70 (wave 0)
    if (tid < 64) {
        float v0 = sc[tid];
        float v1 = (tid + 64 < NT) ? sc[tid + 64] : -1e30f;
        float mx = fmaxf(v0, v1);
        #pragma unroll
        for (int off = 32; off > 0; off >>= 1) mx = fmaxf(mx, __shfl_xor(mx, off, 64));
        float e0 = __expf(v0 - mx);
        float e1 = (tid + 64 < NT) ? __expf(v1 - mx) : 0.0f;
        float ssum = e0 + e1;
        #pragma unroll
        for (int off = 32; off > 0; off >>= 1) ssum += __shfl_xor(ssum, off, 64);
        sc[tid] = e0;
        if (tid + 64 < NT) sc[tid + 64] = e1;
        if (tid == 0) inv_s = 1.0f / ssum;
    }
    __syncthreads();
    float inv = inv_s;
    for (int j = tid; j < NH; j += 256) {
        float acc = 0.0f;
        #pragma unroll 7
        for (int t = 0; t < NT; t++) acc += sc[t] * (float)tup[t][j];
        H[s * NH + j] = acc * inv;
    }
}

// ---------------------------------------------------------------------------
// Bag attention + logits + BCE loss.
// ---------------------------------------------------------------------------
__global__ __launch_bounds__(256)
void bag_kernel(const float* __restrict__ H, const int* __restrict__ label,
                const float* __restrict__ sen_a, const float* __restrict__ sen_r,
                const float* __restrict__ rel, const float* __restrict__ sen_d,
                float* __restrict__ out) {
    int b = blockIdx.x;
    int tid = threadIdx.x;
    __shared__ __align__(16) float Hs[NPB][NH];
    __shared__ float e[NPB];
    __shared__ float Sv[NH];
    __shared__ float part[4];
    const float* Hb = H + b * NPB * NH;
    for (int i = tid; i < NPB * NH; i += 256) (&Hs[0][0])[i] = Hb[i];
    __syncthreads();
    int wvv = tid >> 6, lnn = tid & 63;
    for (int n = wvv; n < NPB; n += 4) {
        float p = 0.0f;
        for (int j = lnn; j < NH; j += 64) p += Hs[n][j] * sen_a[j] * sen_r[j];
        #pragma unroll
        for (int off = 32; off > 0; off >>= 1) p += __shfl_down(p, off, 64);
        if (lnn == 0) e[n] = p;
    }
    __syncthreads();
    if (tid == 0) {
        float mx = e[0];
        for (int n = 1; n < NPB; n++) mx = fmaxf(mx, e[n]);
        float sum = 0.0f;
        for (int n = 0; n < NPB; n++) { float v = __expf(e[n] - mx); e[n] = v; sum += v; }
        float inv = 1.0f / sum;
        for (int n = 0; n < NPB; n++) e[n] *= inv;
    }
    __syncthreads();
    for (int j = tid; j < NH; j += 256) {
        float acc = 0.0f;
        #pragma unroll
        for (int n = 0; n < NPB; n++) acc += e[n] * Hs[n][j];
        Sv[j] = acc;
    }
    __syncthreads();
    float bce = 0.0f;
    if (tid < NREL) {
        float acc = 0.0f;
        #pragma unroll 4
        for (int j = 0; j < NH; j++) acc += Sv[j] * rel[tid * NH + j];
        float l = acc + sen_d[tid];
        out[1 + b * NREL + tid] = l;
        float tgt = (label[b] == tid) ? 1.0f : 0.0f;
        bce = fmaxf(l, 0.0f) - l * tgt + log1pf(__expf(-fabsf(l)));
    }
    #pragma unroll
    for (int off = 32; off > 0; off >>= 1) bce += __shfl_down(bce, off, 64);
    if (lnn == 0) part[wvv] = bce;
    __syncthreads();
    if (tid == 0) {
        float tot = (part[0] + part[1] + part[2] + part[3]) * (1.0f / NREL);
        atomicAdd(out, tot);
    }
}

// ---------------------------------------------------------------------------
extern "C" void kernel_launch(void* const* d_in, const int* in_sizes, int n_in,
                              void* d_out, int out_size, void* d_ws, size_t ws_size,
                              hipStream_t stream) {
    const int*   tok   = (const int*)d_in[0];
    const int*   p1    = (const int*)d_in[1];
    const int*   p2    = (const int*)d_in[2];
    const int*   label = (const int*)d_in[3];
    const float* emb   = (const float*)d_in[4];
    const float* pemb  = (const float*)d_in[5];
    const float* WihF  = (const float*)d_in[6];
    const float* WhhF  = (const float*)d_in[7];
    const float* bihF  = (const float*)d_in[8];
    const float* bhhF  = (const float*)d_in[9];
    const float* WihB  = (const float*)d_in[10];
    const float* WhhB  = (const float*)d_in[11];
    const float* bihB  = (const float*)d_in[12];
    const float* bhhB  = (const float*)d_in[13];
    const float* aw    = (const float*)d_in[14];
    const float* sen_a = (const float*)d_in[15];
    const float* sen_r = (const float*)d_in[16];
    const float* rel   = (const float*)d_in[17];
    const float* sen_d = (const float*)d_in[18];

    // workspace layout (all 16B-aligned chunks)
    const long wpk_bytes = 2L * WPK_DIR_BYTES;                 // 479,232
    const long x_bytes   = (long)NT * NS * XSTR + 2048;        // fp8 + OOB slack
    uchar_t* Wpk  = (uchar_t*)d_ws;
    uchar_t* xbuf = Wpk + wpk_bytes;
    float*   Hbuf = (float*)(xbuf + ((x_bytes + 15) & ~15L));  // 2560*200 f32
    h16*     hfb  = (h16*)(Hbuf + NS * NH);                    // [s][t][NHP] f16
    h16*     hbb  = hfb + (long)NS * HROW;

    hipMemsetAsync(d_out, 0, sizeof(float), stream);   // early: overlaps prep
    prep_gather_kernel<<<PREP_BLOCKS + GATHER_BLOCKS, 256, 0, stream>>>(
        WihF, WhhF, WihB, WhhB, Wpk, tok, p1, p2, emb, pemb, xbuf);
    gru_kernel<<<256, 832, 0, stream>>>(xbuf, Wpk, bihF, bhhF, bihB, bhhB, hfb, hbb);
    attn_kernel<<<NS, 256, 0, stream>>>(hfb, hbb, aw, Hbuf);
    bag_kernel<<<NBAG, 256, 0, stream>>>(Hbuf, label, sen_a, sen_r, rel, sen_d, (float*)d_out);
}